// Round 13
// baseline (765.449 us; speedup 1.0000x reference)
//
#include <hip/hip_runtime.h>
#include <math.h>

#define NB 4
#define NN 4096
#define NC 256
#define NQ 14

typedef __attribute__((ext_vector_type(8))) short short8;
typedef __attribute__((ext_vector_type(4))) float f32x4;
typedef _Float16 f16x8 __attribute__((ext_vector_type(8)));
union UH8 { uint4 u4; f16x8 h8; _Float16 h[8]; };

// ---------------------------------------------------------------- helpers
__device__ __forceinline__ float blockReduceSum256(float v, float* sred) {
    #pragma unroll
    for (int off = 32; off; off >>= 1) v += __shfl_xor(v, off, 64);
    const int lane = threadIdx.x & 63, wid = threadIdx.x >> 6;
    if (lane == 0) sred[wid] = v;
    __syncthreads();
    float s = sred[0] + sred[1] + sred[2] + sred[3];
    __syncthreads();
    return s;
}

// DPP wave64 sum: result lands in lane 63 (VALU-only, no LDS pipe).
__device__ __forceinline__ float dpp_wave_sum63(float x) {
    x += __int_as_float(__builtin_amdgcn_update_dpp(0, __float_as_int(x), 0x111, 0xf, 0xf, true));
    x += __int_as_float(__builtin_amdgcn_update_dpp(0, __float_as_int(x), 0x112, 0xf, 0xf, true));
    x += __int_as_float(__builtin_amdgcn_update_dpp(0, __float_as_int(x), 0x114, 0xf, 0xf, true));
    x += __int_as_float(__builtin_amdgcn_update_dpp(0, __float_as_int(x), 0x118, 0xf, 0xf, true));
    x += __int_as_float(__builtin_amdgcn_update_dpp(0, __float_as_int(x), 0x142, 0xf, 0xf, true));
    x += __int_as_float(__builtin_amdgcn_update_dpp(0, __float_as_int(x), 0x143, 0xf, 0xf, true));
    return x;
}
__device__ __forceinline__ float rdlane(float x, int l) {
    return __int_as_float(__builtin_amdgcn_readlane(__float_as_int(x), l));
}

// ---------------------------------------------------------------- generic GEMM
// out[M,256] = A @ W[256,256], M = 16384. Proven fp32 tiled version.
// gemm_aw3: q/k/v batched via blockIdx.z (one launch, 3x grid in flight).
__device__ __forceinline__ void gemm_aw_body(const float* __restrict__ A,
                                             const float* __restrict__ W,
                                             float* __restrict__ out) {
    const int t = threadIdx.x;
    const int row0 = blockIdx.y * 64;
    const int cb = blockIdx.x * 128;
    __shared__ __align__(16) float Ast[32][68];   // transposed A tile [k][r]
    __shared__ __align__(16) float Wt[32][132];   // W tile [k][c]
    const int r0 = (t & 15) * 4;
    const int c0 = (t >> 4) * 8;
    const int ar = t >> 2;          // 0..63
    const int ak = (t & 3) * 8;     // 0,8,16,24
    const int wr = t >> 3;          // 0..31
    const int wc = (t & 7) * 16;    // 0..112
    float acc[4][8];
    #pragma unroll
    for (int i = 0; i < 4; i++)
        #pragma unroll
        for (int j = 0; j < 8; j++) acc[i][j] = 0.f;

    for (int k0 = 0; k0 < 256; k0 += 32) {
        const float* asrc = A + (size_t)(row0 + ar) * 256 + k0 + ak;
        float4 a0 = *(const float4*)asrc;
        float4 a1 = *(const float4*)(asrc + 4);
        const float* wsrc = W + (size_t)(k0 + wr) * 256 + cb + wc;
        float4 w0 = *(const float4*)wsrc;
        float4 w1 = *(const float4*)(wsrc + 4);
        float4 w2 = *(const float4*)(wsrc + 8);
        float4 w3 = *(const float4*)(wsrc + 12);
        __syncthreads();
        Ast[ak + 0][ar] = a0.x; Ast[ak + 1][ar] = a0.y;
        Ast[ak + 2][ar] = a0.z; Ast[ak + 3][ar] = a0.w;
        Ast[ak + 4][ar] = a1.x; Ast[ak + 5][ar] = a1.y;
        Ast[ak + 6][ar] = a1.z; Ast[ak + 7][ar] = a1.w;
        *(float4*)&Wt[wr][wc + 0] = w0;
        *(float4*)&Wt[wr][wc + 4] = w1;
        *(float4*)&Wt[wr][wc + 8] = w2;
        *(float4*)&Wt[wr][wc + 12] = w3;
        __syncthreads();
        #pragma unroll
        for (int kk = 0; kk < 32; kk++) {
            const float4 a4 = *(const float4*)&Ast[kk][r0];
            const float4 wa = *(const float4*)&Wt[kk][c0];
            const float4 wb = *(const float4*)&Wt[kk][c0 + 4];
            const float av[4] = {a4.x, a4.y, a4.z, a4.w};
            const float wv[8] = {wa.x, wa.y, wa.z, wa.w, wb.x, wb.y, wb.z, wb.w};
            #pragma unroll
            for (int i = 0; i < 4; i++)
                #pragma unroll
                for (int j = 0; j < 8; j++) acc[i][j] += av[i] * wv[j];
        }
    }
    #pragma unroll
    for (int i = 0; i < 4; i++) {
        float* dst = out + (size_t)(row0 + r0 + i) * 256 + cb + c0;
        *(float4*)dst = make_float4(acc[i][0], acc[i][1], acc[i][2], acc[i][3]);
        *(float4*)(dst + 4) = make_float4(acc[i][4], acc[i][5], acc[i][6], acc[i][7]);
    }
}

__global__ __launch_bounds__(256) void gemm_aw3(const float* __restrict__ A0,
                                                const float* __restrict__ W0,
                                                float* __restrict__ O0,
                                                const float* __restrict__ A1,
                                                const float* __restrict__ W1,
                                                float* __restrict__ O1,
                                                const float* __restrict__ A2,
                                                const float* __restrict__ W2,
                                                float* __restrict__ O2) {
    const int z = blockIdx.z;
    const float* A = (z == 0) ? A0 : (z == 1) ? A1 : A2;
    const float* W = (z == 0) ? W0 : (z == 1) ? W1 : W2;
    float* O = (z == 0) ? O0 : (z == 1) ? O1 : O2;
    gemm_aw_body(A, W, O);
}

// ---------------------------------------------------------------- prep kernels
__global__ __launch_bounds__(256) void prep_wqk(const float* __restrict__ Wqs,
                                                const float* __restrict__ Wks,
                                                float* __restrict__ Wqk2) {
    __shared__ __align__(16) float srow[512];
    const int c1 = blockIdx.x, c2 = threadIdx.x;
    srow[c2] = Wqs[c1 * 512 + c2];
    srow[c2 + 256] = Wqs[c1 * 512 + 256 + c2];
    __syncthreads();
    const float* wk = Wks + (size_t)c2 * 512;
    float acc = 0.f;
    for (int d = 0; d < 512; d += 4) {
        float4 a = *(const float4*)&srow[d];
        float4 b = *(const float4*)(wk + d);
        acc += a.x * b.x + a.y * b.y + a.z * b.z + a.w * b.w;
    }
    Wqk2[c1 * 256 + c2] = acc * 0.044194173824159216f;  // 1/sqrt(512)
}

__global__ __launch_bounds__(256) void prep_wcomb(const float* __restrict__ Wvs,
                                                  const float* __restrict__ Wfc,
                                                  float* __restrict__ Wcomb) {
    __shared__ float srow[512];
    const int c1 = blockIdx.x, c2 = threadIdx.x;
    srow[c2] = Wvs[c1 * 512 + c2];
    srow[c2 + 256] = Wvs[c1 * 512 + 256 + c2];
    __syncthreads();
    float acc = 0.f;
    for (int d = 0; d < 512; d++) acc += srow[d] * Wfc[d * 256 + c2];
    Wcomb[c1 * 256 + c2] = acc;
}

__global__ __launch_bounds__(256) void k_seed(const float* __restrict__ sv,
                                              const float* __restrict__ Ws,
                                              const float* __restrict__ Wqk2,
                                              float* __restrict__ seed,
                                              float* __restrict__ qhk) {
    const int q = blockIdx.x, b = blockIdx.y, c = threadIdx.x;
    __shared__ float ssv[256];
    __shared__ float sseed[256];
    ssv[c] = sv[((size_t)b * 256 + c) * 14 + q];
    __syncthreads();
    float acc = 0.f;
    for (int d = 0; d < 256; d++) acc += ssv[d] * Ws[d * 256 + c];
    seed[((size_t)b * 14 + q) * 256 + c] = acc;
    sseed[c] = acc;
    __syncthreads();
    float a2 = 0.f;
    for (int d = 0; d < 256; d++) a2 += sseed[d] * Wqk2[d * 256 + c];
    qhk[((size_t)b * 14 + q) * 256 + c] = a2;
}

// vv [b][m][c] fp32 -> vvT_h [b][c][m] fp16. grid(64,4,4), block 256.
__global__ __launch_bounds__(256) void k_vvhalf(const float* __restrict__ vv,
                                                _Float16* __restrict__ vvT_h) {
    __shared__ float tile[64][65];   // [c][m]
    const int b = blockIdx.z, c0 = blockIdx.y * 64, m0 = blockIdx.x * 64;
    const int t = threadIdx.x;
    #pragma unroll
    for (int i = 0; i < 4; i++) {
        const int m = (t >> 4) + i * 16;
        const float4 v4 = *(const float4*)(vv + ((size_t)b * 4096 + m0 + m) * 256 + c0 + (t & 15) * 4);
        tile[(t & 15) * 4 + 0][m] = v4.x;
        tile[(t & 15) * 4 + 1][m] = v4.y;
        tile[(t & 15) * 4 + 2][m] = v4.z;
        tile[(t & 15) * 4 + 3][m] = v4.w;
    }
    __syncthreads();
    const int c = t >> 2, mo = (t & 3) * 16;
    UH8 o0, o1;
    #pragma unroll
    for (int j = 0; j < 8; j++) {
        o0.h[j] = (_Float16)tile[c][mo + j];
        o1.h[j] = (_Float16)tile[c][mo + 8 + j];
    }
    const size_t off = ((size_t)b * 256 + c0 + c) * 4096 + m0 + mo;
    *(uint4*)(vvT_h + off) = o0.u4;
    *(uint4*)(vvT_h + off + 8) = o1.u4;
}

// ---------------------------------------------------------------- stage-2 attention
__global__ __launch_bounds__(256) void k_logits1(const float* __restrict__ kk,
                                                 const float* __restrict__ qhk,
                                                 const int* __restrict__ supp,
                                                 float* __restrict__ logits) {
    const int b = blockIdx.y;
    const int n = blockIdx.x * 256 + threadIdx.x;
    __shared__ __align__(16) float sq[14][256];
    for (int i = threadIdx.x; i < 14 * 256; i += 256) sq[i >> 8][i & 255] = qhk[b * 14 * 256 + i];
    __syncthreads();
    float acc[14];
    #pragma unroll
    for (int q = 0; q < 14; q++) acc[q] = 0.f;
    const float* krow = kk + ((size_t)b * 4096 + n) * 256;
    for (int c = 0; c < 256; c += 4) {
        const float4 k4 = *(const float4*)(krow + c);
        #pragma unroll
        for (int q = 0; q < 14; q++) {
            const float4 a4 = *(const float4*)&sq[q][c];
            acc[q] += k4.x * a4.x + k4.y * a4.y + k4.z * a4.z + k4.w * a4.w;
        }
    }
    const bool msk = (supp[b * 4096 + n] == 0);
    #pragma unroll
    for (int q = 0; q < 14; q++)
        logits[((size_t)b * 14 + q) * 4096 + n] = msk ? -1e9f : acc[q];
}

__global__ __launch_bounds__(256) void k_softmax1(float* __restrict__ logits) {
    const int b = blockIdx.y, qq = blockIdx.x, t = threadIdx.x;
    __shared__ __align__(16) float sl[4096];
    __shared__ float sred[8];
    float* row = logits + ((size_t)b * 14 + qq) * 4096;
    float mx = -3e38f;
    for (int i = t; i < 4096; i += 256) { float v = row[i]; sl[i] = v; mx = fmaxf(mx, v); }
    #pragma unroll
    for (int off = 32; off; off >>= 1) mx = fmaxf(mx, __shfl_xor(mx, off, 64));
    if ((t & 63) == 0) sred[t >> 6] = mx;
    __syncthreads();
    mx = fmaxf(fmaxf(sred[0], sred[1]), fmaxf(sred[2], sred[3]));
    __syncthreads();
    float s = 0.f;
    for (int i = t; i < 4096; i += 256) { float e = expf(sl[i] - mx); sl[i] = e; s += e; }
    #pragma unroll
    for (int off = 32; off; off >>= 1) s += __shfl_xor(s, off, 64);
    if ((t & 63) == 0) sred[t >> 6] = s;
    __syncthreads();
    s = sred[0] + sred[1] + sred[2] + sred[3];
    const float inv = 1.f / s;
    for (int i = t; i < 4096; i += 256) row[i] = sl[i] * inv;
}

__global__ __launch_bounds__(256) void k_ctxv(const float* __restrict__ A,
                                              const float* __restrict__ vv,
                                              float* __restrict__ part) {
    const int b = blockIdx.y, ch = blockIdx.x, c = threadIdx.x;
    const int n0 = ch * 256;
    __shared__ __align__(16) float sA[14][256];
    for (int i = c; i < 14 * 256; i += 256) {
        int qq = i >> 8, j = i & 255;
        sA[qq][j] = A[((size_t)b * 14 + qq) * 4096 + n0 + j];
    }
    __syncthreads();
    float acc[14];
    #pragma unroll
    for (int q = 0; q < 14; q++) acc[q] = 0.f;
    for (int n = 0; n < 256; n += 4) {
        const float v0 = vv[((size_t)b * 4096 + n0 + n + 0) * 256 + c];
        const float v1 = vv[((size_t)b * 4096 + n0 + n + 1) * 256 + c];
        const float v2 = vv[((size_t)b * 4096 + n0 + n + 2) * 256 + c];
        const float v3 = vv[((size_t)b * 4096 + n0 + n + 3) * 256 + c];
        #pragma unroll
        for (int q = 0; q < 14; q++) {
            const float4 a4 = *(const float4*)&sA[q][n];
            acc[q] += a4.x * v0 + a4.y * v1 + a4.z * v2 + a4.w * v3;
        }
    }
    #pragma unroll
    for (int q = 0; q < 14; q++) part[(((size_t)b * 16 + ch) * 14 + q) * 256 + c] = acc[q];
}

__global__ __launch_bounds__(256) void k_proto(const float* __restrict__ part,
                                               const float* __restrict__ Wcomb,
                                               const float* __restrict__ bfc,
                                               const float* __restrict__ seed,
                                               const float* __restrict__ lng,
                                               const float* __restrict__ lnb,
                                               const float* __restrict__ Wsk,
                                               const float* __restrict__ Wsq,
                                               float* __restrict__ pkn,
                                               float* __restrict__ pqn) {
    const int q = blockIdx.x, b = blockIdx.y, c = threadIdx.x;
    __shared__ float sctx[256];
    __shared__ float sproto[256];
    __shared__ float sred[8];
    float cv = 0.f;
    for (int ch = 0; ch < 16; ch++) cv += part[(((size_t)b * 16 + ch) * 14 + q) * 256 + c];
    sctx[c] = cv;
    __syncthreads();
    float pre = 0.f;
    for (int d = 0; d < 256; d++) pre += sctx[d] * Wcomb[d * 256 + c];
    pre += bfc[c] + seed[((size_t)b * 14 + q) * 256 + c];
    const float mu = blockReduceSum256(pre, sred) * (1.f / 256.f);
    const float dv = pre - mu;
    const float var = blockReduceSum256(dv * dv, sred) * (1.f / 256.f);
    const float proto = dv * (1.f / sqrtf(var + 1e-5f)) * lng[c] + lnb[c];
    sproto[c] = proto;
    __syncthreads();
    float pk = 0.f, pq = 0.f;
    for (int d = 0; d < 256; d++) {
        const float sp = sproto[d];
        pk += sp * Wsk[d * 256 + c];
        pq += sp * Wsq[d * 256 + c];
    }
    const float nk = blockReduceSum256(pk * pk, sred);
    const float nq = blockReduceSum256(pq * pq, sred);
    pkn[((size_t)b * 14 + q) * 256 + c] = pk / fmaxf(sqrtf(nk), 1e-12f);
    pqn[((size_t)b * 14 + q) * 256 + c] = pq / fmaxf(sqrtf(nq), 1e-12f);
}

__global__ __launch_bounds__(256) void k_q2p(const float* __restrict__ qs,
                                             const float* __restrict__ kk,
                                             const float* __restrict__ pkn,
                                             const float* __restrict__ pqn,
                                             float* __restrict__ aq2p,
                                             float* __restrict__ attc,
                                             int* __restrict__ sidq) {
    const int b = blockIdx.y;
    const int n = blockIdx.x * 256 + threadIdx.x;
    __shared__ __align__(16) float spk[14][256];
    __shared__ __align__(16) float spq[14][256];
    for (int i = threadIdx.x; i < 14 * 256; i += 256) {
        spk[i >> 8][i & 255] = pkn[b * 14 * 256 + i];
        spq[i >> 8][i & 255] = pqn[b * 14 * 256 + i];
    }
    __syncthreads();
    float aq[14], ak[14];
    #pragma unroll
    for (int q = 0; q < 14; q++) { aq[q] = 0.f; ak[q] = 0.f; }
    float nq = 0.f, nk = 0.f;
    const float* qrow = qs + ((size_t)b * 4096 + n) * 256;
    const float* krow = kk + ((size_t)b * 4096 + n) * 256;
    for (int c = 0; c < 256; c += 4) {
        const float4 q4 = *(const float4*)(qrow + c);
        const float4 k4 = *(const float4*)(krow + c);
        nq += q4.x * q4.x + q4.y * q4.y + q4.z * q4.z + q4.w * q4.w;
        nk += k4.x * k4.x + k4.y * k4.y + k4.z * k4.z + k4.w * k4.w;
        #pragma unroll
        for (int q = 0; q < 14; q++) {
            const float4 p4 = *(const float4*)&spk[q][c];
            const float4 p4b = *(const float4*)&spq[q][c];
            aq[q] += q4.x * p4.x + q4.y * p4.y + q4.z * p4.z + q4.w * p4.w;
            ak[q] += k4.x * p4b.x + k4.y * p4b.y + k4.z * p4b.z + k4.w * p4b.w;
        }
    }
    const float sq_ = 1.f / fmaxf(sqrtf(nq), 1e-12f);
    const float sk_ = 1.f / fmaxf(sqrtf(nk), 1e-12f);
    float* aqrow = aq2p + ((size_t)b * 4096 + n) * 14;
    float* akrow = attc + ((size_t)b * 4096 + n) * 14;
    int best = 0;
    float bv = -3e38f;
    #pragma unroll
    for (int q = 0; q < 14; q++) {
        const float v = aq[q] * sq_;
        aqrow[q] = v;
        if (v > bv) { bv = v; best = q; }
        akrow[q] = ak[q] * sk_;
    }
    sidq[b * 4096 + n] = best;
}

// ---------------------------------------------------------------- Sinkhorn
// R8 structure (best: 185 us). NEW: the opaque "+v" K pin moved INSIDE the
// iteration. R7-R12 counters imply K[8][15] lives in AGPRs (unified file;
// VGPR_Count 72 < the 120 K needs, no scratch traffic, yet ~240 extra
// issue-slots/iter = one v_accvgpr_read per K access). The per-iteration pin
// creates a loop-carried VGPR-class SSA chain, forcing permanent VGPR
// residency (~180 live VGPRs < 256 cap at (512,1)).
__global__ __launch_bounds__(512, 1) void k_sinkhorn(const float* __restrict__ attc,
                                                     const int* __restrict__ supp,
                                                     const int* __restrict__ valid,
                                                     _Float16* __restrict__ as2ph,
                                                     int* __restrict__ code) {
    const int b = blockIdx.x;
    const int t = threadIdx.x;
    const int lane = t & 63, wid = t >> 6;   // 8 waves
    __shared__ __align__(16) float wred[2][15][8];
    __shared__ float sbg[8];
    float K[8][15], u[8];
    float bgcnt = 0.f;
    #pragma unroll
    for (int j = 0; j < 8; j++) {
        const int n = t + j * 512;
        const int sm = supp[b * 4096 + n];
        bgcnt += (sm == 0) ? 1.f : 0.f;
        const float* arow = attc + ((size_t)b * 4096 + n) * 14;
        #pragma unroll
        for (int m = 0; m < 14; m++) K[j][m] = expf(-20.f * (1.f - arow[m]));
        K[j][14] = (sm > 0) ? expf(-40.f) : 1.f;
        u[j] = 1.f / 4096.f;
    }
    const float bgw = dpp_wave_sum63(bgcnt);
    if (lane == 63) sbg[wid] = bgw;
    __syncthreads();
    float num_bg = 0.f;
    #pragma unroll
    for (int w = 0; w < 8; w++) num_bg += sbg[w];
    const float num_fg = 4096.f - num_bg;
    const float bm_fg = num_fg / (14.f * 4096.f);
    const float bm_tr = num_bg / 4096.f;
    const float a_n = 1.f / 4096.f;
    const float mybm = (lane < 14) ? bm_fg : bm_tr;

    float vloc[15];
    for (int it = 0; it < 100; it++) {
        const int buf = it & 1;
        // pin K in VGPRs each iteration: loop-carried "+v" chain -> the
        // allocator must keep K VGPR-resident (no AGPR shuttling, no remat).
        #pragma unroll
        for (int j = 0; j < 8; j++)
            #pragma unroll
            for (int m = 0; m < 15; m++)
                asm volatile("" : "+v"(K[j][m]));
        float tot[15];
        #pragma unroll
        for (int m = 0; m < 15; m++) {
            float s = 0.f;
            #pragma unroll
            for (int j = 0; j < 8; j++) s += K[j][m] * u[j];
            tot[m] = rdlane(dpp_wave_sum63(s), 63);   // uniform per wave
        }
        float wv = 0.f;
        #pragma unroll
        for (int m = 0; m < 15; m++) wv = (lane == m) ? tot[m] : wv;
        if (lane < 15) wred[buf][lane][wid] = wv;
        __syncthreads();
        float vtmp = 0.f;
        {
            const float4 r0 = *(const float4*)&wred[buf][lane < 15 ? lane : 0][0];
            const float4 r1 = *(const float4*)&wred[buf][lane < 15 ? lane : 0][4];
            const float s = r0.x + r0.y + r0.z + r0.w + r1.x + r1.y + r1.z + r1.w;
            vtmp = mybm * __builtin_amdgcn_rcpf(s + 1e-16f);
        }
        #pragma unroll
        for (int m = 0; m < 15; m++) vloc[m] = rdlane(vtmp, m);
        #pragma unroll
        for (int j = 0; j < 8; j++) {
            float s = 0.f;
            #pragma unroll
            for (int m = 0; m < 15; m++) s += K[j][m] * vloc[m];
            u[j] = a_n * __builtin_amdgcn_rcpf(s + 1e-16f);
        }
    }
    #pragma unroll
    for (int j = 0; j < 8; j++) {
        const int n = t + j * 512;
        float bv = -3e38f;
        int bi = 0;
        union { uint4 u4[4]; _Float16 h[32]; } ob;
        #pragma unroll
        for (int m = 0; m < 14; m++) {
            const float tv = fmaxf(4096.f * u[j] * K[j][m] * vloc[m], 0.f);
            const _Float16 hh = (_Float16)tv;
            ob.h[m] = hh;
            ob.h[16 + m] = (_Float16)(tv - (float)hh);
            if (tv > bv) { bv = tv; bi = m; }
        }
        ob.h[14] = (_Float16)0.f; ob.h[15] = (_Float16)0.f;
        ob.h[30] = (_Float16)0.f; ob.h[31] = (_Float16)0.f;
        uint4* dst = (uint4*)(as2ph + ((size_t)(b * 4096 + n)) * 32);
        dst[0] = ob.u4[0]; dst[1] = ob.u4[1];
        dst[2] = ob.u4[2]; dst[3] = ob.u4[3];
        int msk = 1 << bi;
        if (bi == 0) msk |= (1 << 12);
        else if (bi == 12) msk |= 1;
        else if (bi == 3) msk |= (1 << 11);
        else if (bi == 11) msk |= (1 << 3);
        code[b * 4096 + n] = msk | (valid[b * 4096 + n] << 14);
    }
}

// ---------------------------------------------------------------- lam table
__global__ __launch_bounds__(256) void k_lamtab(const int* __restrict__ code,
                                                int* __restrict__ lamtab) {
    const int b = blockIdx.x, t = threadIdx.x;
    __shared__ int sm0[4], sm1[4];
    int m0 = 0, m1 = 0;
    for (int m = t; m < 4096; m += 256) {
        const int c = code[b * 4096 + m];
        const int mask = c & 0x3fff;
        const int v = c >> 14;
        const int nmask = (~mask) & 0x3fff;
        if (v == 0) { m0 |= mask; m1 |= nmask; }
        else { m1 |= mask; }
    }
    #pragma unroll
    for (int off = 32; off; off >>= 1) {
        m0 |= __shfl_xor(m0, off, 64);
        m1 |= __shfl_xor(m1, off, 64);
    }
    if ((t & 63) == 0) { sm0[t >> 6] = m0; sm1[t >> 6] = m1; }
    __syncthreads();
    if (t == 0) {
        lamtab[b * 2 + 0] = sm0[0] | sm0[1] | sm0[2] | sm0[3];
        lamtab[b * 2 + 1] = sm1[0] | sm1[1] | sm1[2] | sm1[3];
    }
}

// ---------------------------------------------------------------- fused P + PV
__global__ __launch_bounds__(512, 2) void k_fused(const float* __restrict__ aq2p,
                                                  const _Float16* __restrict__ as2ph,
                                                  const int* __restrict__ code,
                                                  const int* __restrict__ sidq,
                                                  const int* __restrict__ lamtab,
                                                  const _Float16* __restrict__ vvT_h,
                                                  float* __restrict__ y) {
    const int bid = blockIdx.x;
    const int xcd = bid & 7, slot = bid >> 3;
    const int b = xcd >> 1;                       // 2 XCDs per batch
    const int n0 = ((xcd & 1) * 64 + slot) * 32;
    const int t = threadIdx.x;
    const int l = t & 63, wv = t >> 6;
    const int wn = wv & 1, wcS = wv >> 1;         // S-phase wave role
    const int quad = l >> 4, lr = l & 15;

    __shared__ __align__(16) _Float16 Pl[2][32 * 128];  // double-buffered P tile
    __shared__ float rsl[4][32];
    __shared__ int ssq[32], sml[32];
    __shared__ float rinv_s[32];

    if (t < 32) {
        const int sq = sidq[b * 4096 + n0 + t];
        const int lm0 = lamtab[b * 2], lm1 = lamtab[b * 2 + 1];
        ssq[t] = sq;
        sml[t] = ((lm0 >> sq) & 1) ? 0 : (((lm1 >> sq) & 1) ? 1 : 2);
    }
    __syncthreads();
    int sqp = 0;
    #pragma unroll
    for (int r = 0; r < 4; r++) {
        const int row_l = wn * 16 + quad * 4 + r;
        sqp |= (ssq[row_l] & 31) << (r * 8);
        sqp |= (sml[row_l] & 3) << (r * 8 + 5);
    }
    UH8 a1, a2;
    {
        const float* arow = aq2p + ((size_t)(b * 4096 + n0 + wn * 16 + lr)) * 14;
        const int kb = (quad & 1) * 8;
        #pragma unroll
        for (int j = 0; j < 8; j++) {
            const int kk2 = kb + j;
            const float f = (kk2 < 14) ? arow[kk2] : 0.f;
            const _Float16 hi = (_Float16)f;
            a1.h[j] = hi;
            a2.h[j] = (quad < 2) ? (_Float16)(f - (float)hi) : (_Float16)0.f;
        }
    }
    const _Float16* a2base = as2ph + (size_t)b * 4096 * 32 + quad * 8;
    const int* cbase = code + b * 4096;
    const _Float16* bvb0 = vvT_h + ((size_t)(b * 256 + wv * 32 + lr)) * 4096 + quad * 8;
    const _Float16* bvb1 = bvb0 + (size_t)16 * 4096;

    UH8 bS[2];
    int cdr[2];
    #pragma unroll
    for (int i = 0; i < 2; i++) {
        const int m = (wcS * 2 + i) * 16 + lr;
        bS[i].u4 = *(const uint4*)(a2base + (size_t)m * 32);
        cdr[i] = cbase[m];
    }
    UH8 bA[8], bB[8];
    #pragma unroll
    for (int ms = 0; ms < 4; ms++) {
        bA[ms * 2 + 0].u4 = *(const uint4*)(bvb0 + ms * 32);
        bA[ms * 2 + 1].u4 = *(const uint4*)(bvb1 + ms * 32);
    }
    f32x4 acc[2][2];
    #pragma unroll
    for (int fr = 0; fr < 2; fr++)
        #pragma unroll
        for (int ct = 0; ct < 2; ct++) acc[fr][ct] = (f32x4){0.f, 0.f, 0.f, 0.f};
    float rs4[4] = {0.f, 0.f, 0.f, 0.f};

#define FCHUNK(CUR, NXT, CH, LAST)                                             \
  {                                                                            \
    _Float16* PlW = Pl[(CH) & 1];                                              \
    _Pragma("unroll")                                                          \
    for (int i = 0; i < 2; i++) {                                              \
      f32x4 S = (f32x4){0.f, 0.f, 0.f, 0.f};                                   \
      S = __builtin_amdgcn_mfma_f32_16x16x32_f16(a1.h8, bS[i].h8, S, 0, 0, 0); \
      S = __builtin_amdgcn_mfma_f32_16x16x32_f16(a2.h8, bS[i].h8, S, 0, 0, 0); \
      const int cd = cdr[i];                                                   \
      const int mlocal = (wcS * 2 + i) * 16 + lr;                              \
      _Pragma("unroll")                                                        \
      for (int r = 0; r < 4; r++) {                                            \
        const int sq_r = (sqp >> (r * 8)) & 31;                                \
        const int ml_r = (sqp >> (r * 8 + 5)) & 3;                             \
        const int lvl = (cd >> 14) + 1 - ((cd >> sq_r) & 1);                   \
        const float p = (lvl == ml_r) ? __expf(S[r]) : 0.f;                    \
        rs4[r] += p;                                                           \
        const int nrow = wn * 16 + quad * 4 + r;                               \
        PlW[nrow * 128 + (mlocal ^ ((nrow & 7) << 3))] = (_Float16)p;          \
      }                                                                        \
    }                                                                          \
    if (!(LAST)) {                                                             \
      const int mcn = ((CH) + 1) * 128;                                        \
      _Pragma("unroll")                                                        \
      for (int i = 0; i < 2; i++) {                                            \
        const int m = mcn + (wcS * 2 + i) * 16 + lr;                           \
        bS[i].u4 = *(const uint4*)(a2base + (size_t)m * 32);                   \
        cdr[i] = cbase[m];                                                     \
      }                                                                        \
      _Pragma("unroll")                                                        \
      for (int ms = 0; ms < 4; ms++) {                                         \
        NXT[ms * 2 + 0].u4 = *(const uint4*)(bvb0 + mcn + ms * 32);            \
        NXT[ms * 2 + 1].u4 = *(const uint4*)(bvb1 + mcn + ms * 32);            \
      }                                                                        \
    }                                                                          \
    asm volatile("s_waitcnt lgkmcnt(0)" ::: "memory");                         \
    __builtin_amdgcn_s_barrier();                                              \
    asm volatile("" ::: "memory");                                             \
    const _Float16* PlR = Pl[(CH) & 1];                                        \
    __builtin_amdgcn_s_setprio(1);                                             \
    _Pragma("unroll")                                                          \
    for (int ms = 0; ms < 4; ms++) {                                           \
      UH8 aP0, aP1;                                                            \
      const int mb = ms * 32 + quad * 8;                                       \
      const int msw = mb ^ ((lr & 7) << 3);                                    \
      aP0.u4 = *(const uint4*)&PlR[lr * 128 + msw];                            \
      aP1.u4 = *(const uint4*)&PlR[(16 + lr) * 128 + msw];                     \
      acc[0][0] = __builtin_amdgcn_mfma_f32_16x16x32_f16(aP0.h8, CUR[ms * 2 + 0].h8, acc[0][0], 0, 0, 0); \
      acc[0][1] = __builtin_amdgcn_mfma_f32_16x16x32_f16(aP0.h8, CUR[ms * 2 + 1].h8, acc[0][1], 0, 0, 0); \
      acc[1][0] = __builtin_amdgcn_mfma_f32_16x16x32_f16(aP1.h8, CUR[ms * 2 + 0].h8, acc[1][0], 0, 0, 0); \
      acc[1][1] = __builtin_amdgcn_mfma_f32_16x16x32_f16(aP1.h8, CUR[ms * 2 + 1].h8, acc[1][1], 0, 0, 0); \
    }                                                                          \
    __builtin_amdgcn_s_setprio(0);                                             \
  }

    #pragma unroll 1
    for (int ch2 = 0; ch2 < 16; ch2++) {
        FCHUNK(bA, bB, ch2 * 2, false);
        FCHUNK(bB, bA, ch2 * 2 + 1, (ch2 == 15));
    }
#undef FCHUNK

    #pragma unroll
    for (int r = 0; r < 4; r++) {
        float v = rs4[r];
        v += __shfl_xor(v, 1, 64);
        v += __shfl_xor(v, 2, 64);
        v += __shfl_xor(v, 4, 64);
        v += __shfl_xor(v, 8, 64);
        rs4[r] = v;
    }
    __syncthreads();
    if (lr == 0) {
        #pragma unroll
        for (int r = 0; r < 4; r++) rsl[wcS][wn * 16 + quad * 4 + r] = rs4[r];
    }
    __syncthreads();
    if (t < 32) rinv_s[t] = 1.f / (rsl[0][t] + rsl[1][t] + rsl[2][t] + rsl[3][t]);
    __syncthreads();
    #pragma unroll
    for (int fr = 0; fr < 2; fr++)
        #pragma unroll
        for (int ct = 0; ct < 2; ct++)
            #pragma unroll
            for (int j = 0; j < 4; j++) {
                const int rowd = fr * 16 + quad * 4 + j;
                y[((size_t)b * 4096 + n0 + rowd) * 256 + wv * 32 + ct * 16 + lr] =
                    acc[fr][ct][j] * rinv_s[rowd];
            }
}

// ---------------------------------------------------------------- launch
extern "C" void kernel_launch(void* const* d_in, const int* in_sizes, int n_in,
                              void* d_out, int out_size, void* d_ws, size_t ws_size,
                              hipStream_t stream) {
    (void)in_sizes; (void)n_in; (void)out_size; (void)ws_size;
    const float* q    = (const float*)d_in[0];
    const float* k    = (const float*)d_in[1];
    const float* v    = (const float*)d_in[2];
    const float* sv   = (const float*)d_in[3];
    const int*  valid = (const int*)d_in[4];
    const int*  supp  = (const int*)d_in[5];
    const float* Wq   = (const float*)d_in[6];
    const float* Wk   = (const float*)d_in[7];
    const float* Wv   = (const float*)d_in[8];
    const float* Ws   = (const float*)d_in[9];
    const float* Wsq  = (const float*)d_in[10];
    const float* Wsk  = (const float*)d_in[11];
    const float* Wproj= (const float*)d_in[12];
    const float* Wqs  = (const float*)d_in[13];
    const float* Wks  = (const float*)d_in[14];
    const float* Wvs  = (const float*)d_in[15];
    const float* Wfc  = (const float*)d_in[16];
    const float* bfc  = (const float*)d_in[17];
    const float* lng  = (const float*)d_in[18];
    const float* lnb  = (const float*)d_in[19];

    float* ws = (float*)d_ws;
    // as2ph (fp16 4x4096x32 = 1 MB) overlays qs (dead after k_q2p)
    _Float16* as2ph = (_Float16*)ws;
    float* qs   = ws + 0;
    float* kk   = ws + 4194304;
    float* vv   = ws + 8388608;
    float* y0   = ws + 33554432;
    float* wqk2 = ws + 37748736;
    float* wcomb= ws + 37814272;
    float* seed = ws + 37879808;
    float* qhk  = ws + 37894144;
    float* logA = ws + 37908480;
    float* cpart= ws + 38137856;
    float* pkn  = ws + 38367232;
    float* pqn  = ws + 38381568;
    float* aq2p = ws + 38395904;
    float* attc = ws + 38625280;
    int* code   = (int*)(ws + 39084032);
    int* sidq   = (int*)(ws + 39100416);
    int* lamtab = (int*)(ws + 39116800);
    _Float16* vvT_h = (_Float16*)(ws + 39133216);

    gemm_aw3<<<dim3(2, 256, 3), 256, 0, stream>>>(q, Wq, qs, k, Wk, kk, v, Wv, vv);
    k_vvhalf<<<dim3(64, 4, 4), 256, 0, stream>>>(vv, vvT_h);
    prep_wqk<<<256, 256, 0, stream>>>(Wqs, Wks, wqk2);
    prep_wcomb<<<256, 256, 0, stream>>>(Wvs, Wfc, wcomb);
    k_seed<<<dim3(14, 4), 256, 0, stream>>>(sv, Ws, wqk2, seed, qhk);
    k_logits1<<<dim3(16, 4), 256, 0, stream>>>(kk, qhk, supp, logA);
    k_softmax1<<<dim3(14, 4), 256, 0, stream>>>(logA);
    k_ctxv<<<dim3(16, 4), 256, 0, stream>>>(logA, vv, cpart);
    k_proto<<<dim3(14, 4), 256, 0, stream>>>(cpart, wcomb, bfc, seed, lng, lnb, Wsk, Wsq, pkn, pqn);
    k_q2p<<<dim3(16, 4), 256, 0, stream>>>(qs, kk, pkn, pqn, aq2p, attc, sidq);
    k_sinkhorn<<<4, 512, 0, stream>>>(attc, supp, valid, as2ph, code);
    k_lamtab<<<4, 256, 0, stream>>>(code, lamtab);
    k_fused<<<dim3(512), 512, 0, stream>>>(aq2p, as2ph, code, sidq, lamtab, vvT_h, y0);
    gemm_aw3<<<dim3(2, 256, 1), 256, 0, stream>>>(y0, Wproj, (float*)d_out,
                                                  y0, Wproj, (float*)d_out,
                                                  y0, Wproj, (float*)d_out);
}

// Round 14
// 731.629 us; speedup vs baseline: 1.0462x; 1.0462x over previous
//
#include <hip/hip_runtime.h>
#include <math.h>

#define NB 4
#define NN 4096
#define NC 256
#define NQ 14

typedef __attribute__((ext_vector_type(8))) short short8;
typedef __attribute__((ext_vector_type(4))) float f32x4;
typedef _Float16 f16x8 __attribute__((ext_vector_type(8)));
union UH8 { uint4 u4; f16x8 h8; _Float16 h[8]; };

// ---------------------------------------------------------------- helpers
__device__ __forceinline__ float blockReduceSum256(float v, float* sred) {
    #pragma unroll
    for (int off = 32; off; off >>= 1) v += __shfl_xor(v, off, 64);
    const int lane = threadIdx.x & 63, wid = threadIdx.x >> 6;
    if (lane == 0) sred[wid] = v;
    __syncthreads();
    float s = sred[0] + sred[1] + sred[2] + sred[3];
    __syncthreads();
    return s;
}

// DPP wave64 sum: result lands in lane 63 (VALU-only, no LDS pipe).
__device__ __forceinline__ float dpp_wave_sum63(float x) {
    x += __int_as_float(__builtin_amdgcn_update_dpp(0, __float_as_int(x), 0x111, 0xf, 0xf, true));
    x += __int_as_float(__builtin_amdgcn_update_dpp(0, __float_as_int(x), 0x112, 0xf, 0xf, true));
    x += __int_as_float(__builtin_amdgcn_update_dpp(0, __float_as_int(x), 0x114, 0xf, 0xf, true));
    x += __int_as_float(__builtin_amdgcn_update_dpp(0, __float_as_int(x), 0x118, 0xf, 0xf, true));
    x += __int_as_float(__builtin_amdgcn_update_dpp(0, __float_as_int(x), 0x142, 0xf, 0xf, true));
    x += __int_as_float(__builtin_amdgcn_update_dpp(0, __float_as_int(x), 0x143, 0xf, 0xf, true));
    return x;
}
__device__ __forceinline__ float rdlane(float x, int l) {
    return __int_as_float(__builtin_amdgcn_readlane(__float_as_int(x), l));
}

// ---------------------------------------------------------------- generic GEMM
// out[M,256] = A @ W[256,256], M = 16384. Proven fp32 tiled version.
__device__ __forceinline__ void gemm_aw_body(const float* __restrict__ A,
                                             const float* __restrict__ W,
                                             float* __restrict__ out,
                                             float* AstRaw, float* WtRaw) {
    const int t = threadIdx.x;
    const int row0 = blockIdx.y * 64;
    const int cb = blockIdx.x * 128;
    float (*Ast)[68] = (float(*)[68])AstRaw;    // transposed A tile [k][r]
    float (*Wt)[132] = (float(*)[132])WtRaw;    // W tile [k][c]
    const int r0 = (t & 15) * 4;
    const int c0 = (t >> 4) * 8;
    const int ar = t >> 2;          // 0..63
    const int ak = (t & 3) * 8;     // 0,8,16,24
    const int wr = t >> 3;          // 0..31
    const int wc = (t & 7) * 16;    // 0..112
    float acc[4][8];
    #pragma unroll
    for (int i = 0; i < 4; i++)
        #pragma unroll
        for (int j = 0; j < 8; j++) acc[i][j] = 0.f;

    for (int k0 = 0; k0 < 256; k0 += 32) {
        const float* asrc = A + (size_t)(row0 + ar) * 256 + k0 + ak;
        float4 a0 = *(const float4*)asrc;
        float4 a1 = *(const float4*)(asrc + 4);
        const float* wsrc = W + (size_t)(k0 + wr) * 256 + cb + wc;
        float4 w0 = *(const float4*)wsrc;
        float4 w1 = *(const float4*)(wsrc + 4);
        float4 w2 = *(const float4*)(wsrc + 8);
        float4 w3 = *(const float4*)(wsrc + 12);
        __syncthreads();
        Ast[ak + 0][ar] = a0.x; Ast[ak + 1][ar] = a0.y;
        Ast[ak + 2][ar] = a0.z; Ast[ak + 3][ar] = a0.w;
        Ast[ak + 4][ar] = a1.x; Ast[ak + 5][ar] = a1.y;
        Ast[ak + 6][ar] = a1.z; Ast[ak + 7][ar] = a1.w;
        *(float4*)&Wt[wr][wc + 0] = w0;
        *(float4*)&Wt[wr][wc + 4] = w1;
        *(float4*)&Wt[wr][wc + 8] = w2;
        *(float4*)&Wt[wr][wc + 12] = w3;
        __syncthreads();
        #pragma unroll
        for (int kk = 0; kk < 32; kk++) {
            const float4 a4 = *(const float4*)&Ast[kk][r0];
            const float4 wa = *(const float4*)&Wt[kk][c0];
            const float4 wb = *(const float4*)&Wt[kk][c0 + 4];
            const float av[4] = {a4.x, a4.y, a4.z, a4.w};
            const float wv[8] = {wa.x, wa.y, wa.z, wa.w, wb.x, wb.y, wb.z, wb.w};
            #pragma unroll
            for (int i = 0; i < 4; i++)
                #pragma unroll
                for (int j = 0; j < 8; j++) acc[i][j] += av[i] * wv[j];
        }
    }
    #pragma unroll
    for (int i = 0; i < 4; i++) {
        float* dst = out + (size_t)(row0 + r0 + i) * 256 + cb + c0;
        *(float4*)dst = make_float4(acc[i][0], acc[i][1], acc[i][2], acc[i][3]);
        *(float4*)(dst + 4) = make_float4(acc[i][4], acc[i][5], acc[i][6], acc[i][7]);
    }
}

// q/k/v GEMMs (z=0..2) + the two weight-prep kernels folded in as z==3
// (preps are independent of the GEMM outputs; saves 2 launches).
__global__ __launch_bounds__(256) void gemm_aw3p(const float* __restrict__ A0,
                                                 const float* __restrict__ W0,
                                                 float* __restrict__ O0,
                                                 const float* __restrict__ A1,
                                                 const float* __restrict__ W1,
                                                 float* __restrict__ O1,
                                                 const float* __restrict__ A2,
                                                 const float* __restrict__ W2,
                                                 float* __restrict__ O2,
                                                 const float* __restrict__ Wqs,
                                                 const float* __restrict__ Wks,
                                                 float* __restrict__ Wqk2,
                                                 const float* __restrict__ Wvs,
                                                 const float* __restrict__ Wfc,
                                                 float* __restrict__ Wcomb) {
    __shared__ __align__(16) float Ast[32][68];
    __shared__ __align__(16) float Wt[32][132];
    const int z = blockIdx.z;
    if (z == 3) {
        // prep lane: blockIdx.x==0 -> wqk2[c1][*], ==1 -> wcomb[c1][*]
        float* srow = &Ast[0][0];   // reuse gemm LDS (512 floats needed)
        const int c1 = blockIdx.y, c2 = threadIdx.x;
        if (blockIdx.x == 0) {
            srow[c2] = Wqs[c1 * 512 + c2];
            srow[c2 + 256] = Wqs[c1 * 512 + 256 + c2];
            __syncthreads();
            const float* wk = Wks + (size_t)c2 * 512;
            float acc = 0.f;
            for (int d = 0; d < 512; d += 4) {
                float4 a = *(const float4*)&srow[d];
                float4 b = *(const float4*)(wk + d);
                acc += a.x * b.x + a.y * b.y + a.z * b.z + a.w * b.w;
            }
            Wqk2[c1 * 256 + c2] = acc * 0.044194173824159216f;  // 1/sqrt(512)
        } else {
            srow[c2] = Wvs[c1 * 512 + c2];
            srow[c2 + 256] = Wvs[c1 * 512 + 256 + c2];
            __syncthreads();
            float acc = 0.f;
            for (int d = 0; d < 512; d++) acc += srow[d] * Wfc[d * 256 + c2];
            Wcomb[c1 * 256 + c2] = acc;
        }
        return;
    }
    const float* A = (z == 0) ? A0 : (z == 1) ? A1 : A2;
    const float* W = (z == 0) ? W0 : (z == 1) ? W1 : W2;
    float* O = (z == 0) ? O0 : (z == 1) ? O1 : O2;
    gemm_aw_body(A, W, O, &Ast[0][0], &Wt[0][0]);
}

// final projection GEMM (single operand)
__global__ __launch_bounds__(256) void gemm_aw(const float* __restrict__ A,
                                               const float* __restrict__ W,
                                               float* __restrict__ out) {
    __shared__ __align__(16) float Ast[32][68];
    __shared__ __align__(16) float Wt[32][132];
    gemm_aw_body(A, W, out, &Ast[0][0], &Wt[0][0]);
}

__global__ __launch_bounds__(256) void k_seed(const float* __restrict__ sv,
                                              const float* __restrict__ Ws,
                                              const float* __restrict__ Wqk2,
                                              float* __restrict__ seed,
                                              float* __restrict__ qhk) {
    const int q = blockIdx.x, b = blockIdx.y, c = threadIdx.x;
    __shared__ float ssv[256];
    __shared__ float sseed[256];
    ssv[c] = sv[((size_t)b * 256 + c) * 14 + q];
    __syncthreads();
    float acc = 0.f;
    for (int d = 0; d < 256; d++) acc += ssv[d] * Ws[d * 256 + c];
    seed[((size_t)b * 14 + q) * 256 + c] = acc;
    sseed[c] = acc;
    __syncthreads();
    float a2 = 0.f;
    for (int d = 0; d < 256; d++) a2 += sseed[d] * Wqk2[d * 256 + c];
    qhk[((size_t)b * 14 + q) * 256 + c] = a2;
}

// ---------------------------------------------------------------- stage-2 attention
__global__ __launch_bounds__(256) void k_logits1(const float* __restrict__ kk,
                                                 const float* __restrict__ qhk,
                                                 const int* __restrict__ supp,
                                                 float* __restrict__ logits) {
    const int b = blockIdx.y;
    const int n = blockIdx.x * 256 + threadIdx.x;
    __shared__ __align__(16) float sq[14][256];
    for (int i = threadIdx.x; i < 14 * 256; i += 256) sq[i >> 8][i & 255] = qhk[b * 14 * 256 + i];
    __syncthreads();
    float acc[14];
    #pragma unroll
    for (int q = 0; q < 14; q++) acc[q] = 0.f;
    const float* krow = kk + ((size_t)b * 4096 + n) * 256;
    for (int c = 0; c < 256; c += 4) {
        const float4 k4 = *(const float4*)(krow + c);
        #pragma unroll
        for (int q = 0; q < 14; q++) {
            const float4 a4 = *(const float4*)&sq[q][c];
            acc[q] += k4.x * a4.x + k4.y * a4.y + k4.z * a4.z + k4.w * a4.w;
        }
    }
    const bool msk = (supp[b * 4096 + n] == 0);
    #pragma unroll
    for (int q = 0; q < 14; q++)
        logits[((size_t)b * 14 + q) * 4096 + n] = msk ? -1e9f : acc[q];
}

__global__ __launch_bounds__(256) void k_softmax1(float* __restrict__ logits) {
    const int b = blockIdx.y, qq = blockIdx.x, t = threadIdx.x;
    __shared__ __align__(16) float sl[4096];
    __shared__ float sred[8];
    float* row = logits + ((size_t)b * 14 + qq) * 4096;
    float mx = -3e38f;
    for (int i = t; i < 4096; i += 256) { float v = row[i]; sl[i] = v; mx = fmaxf(mx, v); }
    #pragma unroll
    for (int off = 32; off; off >>= 1) mx = fmaxf(mx, __shfl_xor(mx, off, 64));
    if ((t & 63) == 0) sred[t >> 6] = mx;
    __syncthreads();
    mx = fmaxf(fmaxf(sred[0], sred[1]), fmaxf(sred[2], sred[3]));
    __syncthreads();
    float s = 0.f;
    for (int i = t; i < 4096; i += 256) { float e = expf(sl[i] - mx); sl[i] = e; s += e; }
    #pragma unroll
    for (int off = 32; off; off >>= 1) s += __shfl_xor(s, off, 64);
    if ((t & 63) == 0) sred[t >> 6] = s;
    __syncthreads();
    s = sred[0] + sred[1] + sred[2] + sred[3];
    const float inv = 1.f / s;
    for (int i = t; i < 4096; i += 256) row[i] = sl[i] * inv;
}

__global__ __launch_bounds__(256) void k_ctxv(const float* __restrict__ A,
                                              const float* __restrict__ vv,
                                              float* __restrict__ part) {
    const int b = blockIdx.y, ch = blockIdx.x, c = threadIdx.x;
    const int n0 = ch * 256;
    __shared__ __align__(16) float sA[14][256];
    for (int i = c; i < 14 * 256; i += 256) {
        int qq = i >> 8, j = i & 255;
        sA[qq][j] = A[((size_t)b * 14 + qq) * 4096 + n0 + j];
    }
    __syncthreads();
    float acc[14];
    #pragma unroll
    for (int q = 0; q < 14; q++) acc[q] = 0.f;
    for (int n = 0; n < 256; n += 4) {
        const float v0 = vv[((size_t)b * 4096 + n0 + n + 0) * 256 + c];
        const float v1 = vv[((size_t)b * 4096 + n0 + n + 1) * 256 + c];
        const float v2 = vv[((size_t)b * 4096 + n0 + n + 2) * 256 + c];
        const float v3 = vv[((size_t)b * 4096 + n0 + n + 3) * 256 + c];
        #pragma unroll
        for (int q = 0; q < 14; q++) {
            const float4 a4 = *(const float4*)&sA[q][n];
            acc[q] += a4.x * v0 + a4.y * v1 + a4.z * v2 + a4.w * v3;
        }
    }
    #pragma unroll
    for (int q = 0; q < 14; q++) part[(((size_t)b * 16 + ch) * 14 + q) * 256 + c] = acc[q];
}

__global__ __launch_bounds__(256) void k_proto(const float* __restrict__ part,
                                               const float* __restrict__ Wcomb,
                                               const float* __restrict__ bfc,
                                               const float* __restrict__ seed,
                                               const float* __restrict__ lng,
                                               const float* __restrict__ lnb,
                                               const float* __restrict__ Wsk,
                                               const float* __restrict__ Wsq,
                                               float* __restrict__ pkn,
                                               float* __restrict__ pqn) {
    const int q = blockIdx.x, b = blockIdx.y, c = threadIdx.x;
    __shared__ float sctx[256];
    __shared__ float sproto[256];
    __shared__ float sred[8];
    float cv = 0.f;
    for (int ch = 0; ch < 16; ch++) cv += part[(((size_t)b * 16 + ch) * 14 + q) * 256 + c];
    sctx[c] = cv;
    __syncthreads();
    float pre = 0.f;
    for (int d = 0; d < 256; d++) pre += sctx[d] * Wcomb[d * 256 + c];
    pre += bfc[c] + seed[((size_t)b * 14 + q) * 256 + c];
    const float mu = blockReduceSum256(pre, sred) * (1.f / 256.f);
    const float dv = pre - mu;
    const float var = blockReduceSum256(dv * dv, sred) * (1.f / 256.f);
    const float proto = dv * (1.f / sqrtf(var + 1e-5f)) * lng[c] + lnb[c];
    sproto[c] = proto;
    __syncthreads();
    float pk = 0.f, pq = 0.f;
    for (int d = 0; d < 256; d++) {
        const float sp = sproto[d];
        pk += sp * Wsk[d * 256 + c];
        pq += sp * Wsq[d * 256 + c];
    }
    const float nk = blockReduceSum256(pk * pk, sred);
    const float nq = blockReduceSum256(pq * pq, sred);
    pkn[((size_t)b * 14 + q) * 256 + c] = pk / fmaxf(sqrtf(nk), 1e-12f);
    pqn[((size_t)b * 14 + q) * 256 + c] = pq / fmaxf(sqrtf(nq), 1e-12f);
}

__global__ __launch_bounds__(256) void k_q2p(const float* __restrict__ qs,
                                             const float* __restrict__ kk,
                                             const float* __restrict__ pkn,
                                             const float* __restrict__ pqn,
                                             float* __restrict__ aq2p,
                                             float* __restrict__ attc,
                                             int* __restrict__ sidq) {
    const int b = blockIdx.y;
    const int n = blockIdx.x * 256 + threadIdx.x;
    __shared__ __align__(16) float spk[14][256];
    __shared__ __align__(16) float spq[14][256];
    for (int i = threadIdx.x; i < 14 * 256; i += 256) {
        spk[i >> 8][i & 255] = pkn[b * 14 * 256 + i];
        spq[i >> 8][i & 255] = pqn[b * 14 * 256 + i];
    }
    __syncthreads();
    float aq[14], ak[14];
    #pragma unroll
    for (int q = 0; q < 14; q++) { aq[q] = 0.f; ak[q] = 0.f; }
    float nq = 0.f, nk = 0.f;
    const float* qrow = qs + ((size_t)b * 4096 + n) * 256;
    const float* krow = kk + ((size_t)b * 4096 + n) * 256;
    for (int c = 0; c < 256; c += 4) {
        const float4 q4 = *(const float4*)(qrow + c);
        const float4 k4 = *(const float4*)(krow + c);
        nq += q4.x * q4.x + q4.y * q4.y + q4.z * q4.z + q4.w * q4.w;
        nk += k4.x * k4.x + k4.y * k4.y + k4.z * k4.z + k4.w * k4.w;
        #pragma unroll
        for (int q = 0; q < 14; q++) {
            const float4 p4 = *(const float4*)&spk[q][c];
            const float4 p4b = *(const float4*)&spq[q][c];
            aq[q] += q4.x * p4.x + q4.y * p4.y + q4.z * p4.z + q4.w * p4.w;
            ak[q] += k4.x * p4b.x + k4.y * p4b.y + k4.z * p4b.z + k4.w * p4b.w;
        }
    }
    const float sq_ = 1.f / fmaxf(sqrtf(nq), 1e-12f);
    const float sk_ = 1.f / fmaxf(sqrtf(nk), 1e-12f);
    float* aqrow = aq2p + ((size_t)b * 4096 + n) * 14;
    float* akrow = attc + ((size_t)b * 4096 + n) * 14;
    int best = 0;
    float bv = -3e38f;
    #pragma unroll
    for (int q = 0; q < 14; q++) {
        const float v = aq[q] * sq_;
        aqrow[q] = v;
        if (v > bv) { bv = v; best = q; }
        akrow[q] = ak[q] * sk_;
    }
    sidq[b * 4096 + n] = best;
}

// ---------------------------------------------------------------- Sinkhorn + vv transpose
// blocks 0..3: R8/R13 sinkhorn (plateau 185 us, 5 codegen attempts bracket it).
// blocks 4..515: the vv->vvT_h fp16 transpose (formerly k_vvhalf, 1024 blocks
// of 256 thr -> 512 blocks of 512 thr, 2 tiles each) rides on the 252 CUs
// sinkhorn leaves idle -> its ~15 us dispatch disappears entirely.
__global__ __launch_bounds__(512, 1) void k_sinkvv(const float* __restrict__ attc,
                                                   const int* __restrict__ supp,
                                                   const int* __restrict__ valid,
                                                   _Float16* __restrict__ as2ph,
                                                   int* __restrict__ code,
                                                   const float* __restrict__ vv,
                                                   _Float16* __restrict__ vvT_h) {
    const int bid = blockIdx.x;
    __shared__ __align__(16) float wred[2][15][8];
    __shared__ float sbg[8];
    __shared__ float tile2[2][64][65];
    if (bid >= 4) {
        // vv transpose lane: two original 64x64 tiles per block
        const int half = threadIdx.x >> 8;
        const int ob = (bid - 4) * 2 + half;     // 0..1023 original block id
        const int t = threadIdx.x & 255;
        const int b = ob >> 8;
        const int c0 = ((ob >> 6) & 3) * 64;
        const int m0 = (ob & 63) * 64;
        float (*tile)[65] = tile2[half];
        #pragma unroll
        for (int i = 0; i < 4; i++) {
            const int m = (t >> 4) + i * 16;
            const float4 v4 = *(const float4*)(vv + ((size_t)b * 4096 + m0 + m) * 256 + c0 + (t & 15) * 4);
            tile[(t & 15) * 4 + 0][m] = v4.x;
            tile[(t & 15) * 4 + 1][m] = v4.y;
            tile[(t & 15) * 4 + 2][m] = v4.z;
            tile[(t & 15) * 4 + 3][m] = v4.w;
        }
        __syncthreads();
        const int c = t >> 2, mo = (t & 3) * 16;
        UH8 o0, o1;
        #pragma unroll
        for (int j = 0; j < 8; j++) {
            o0.h[j] = (_Float16)tile[c][mo + j];
            o1.h[j] = (_Float16)tile[c][mo + 8 + j];
        }
        const size_t off = ((size_t)b * 256 + c0 + c) * 4096 + m0 + mo;
        *(uint4*)(vvT_h + off) = o0.u4;
        *(uint4*)(vvT_h + off + 8) = o1.u4;
        return;
    }
    const int b = bid;
    const int t = threadIdx.x;
    const int lane = t & 63, wid = t >> 6;   // 8 waves
    float K[8][15], u[8];
    float bgcnt = 0.f;
    #pragma unroll
    for (int j = 0; j < 8; j++) {
        const int n = t + j * 512;
        const int sm = supp[b * 4096 + n];
        bgcnt += (sm == 0) ? 1.f : 0.f;
        const float* arow = attc + ((size_t)b * 4096 + n) * 14;
        #pragma unroll
        for (int m = 0; m < 14; m++) K[j][m] = expf(-20.f * (1.f - arow[m]));
        K[j][14] = (sm > 0) ? expf(-40.f) : 1.f;
        u[j] = 1.f / 4096.f;
    }
    const float bgw = dpp_wave_sum63(bgcnt);
    if (lane == 63) sbg[wid] = bgw;
    __syncthreads();
    float num_bg = 0.f;
    #pragma unroll
    for (int w = 0; w < 8; w++) num_bg += sbg[w];
    const float num_fg = 4096.f - num_bg;
    const float bm_fg = num_fg / (14.f * 4096.f);
    const float bm_tr = num_bg / 4096.f;
    const float a_n = 1.f / 4096.f;
    const float mybm = (lane < 14) ? bm_fg : bm_tr;

    float vloc[15];
    for (int it = 0; it < 100; it++) {
        const int buf = it & 1;
        #pragma unroll
        for (int j = 0; j < 8; j++)
            #pragma unroll
            for (int m = 0; m < 15; m++)
                asm volatile("" : "+v"(K[j][m]));
        float tot[15];
        #pragma unroll
        for (int m = 0; m < 15; m++) {
            float s = 0.f;
            #pragma unroll
            for (int j = 0; j < 8; j++) s += K[j][m] * u[j];
            tot[m] = rdlane(dpp_wave_sum63(s), 63);   // uniform per wave
        }
        float wv = 0.f;
        #pragma unroll
        for (int m = 0; m < 15; m++) wv = (lane == m) ? tot[m] : wv;
        if (lane < 15) wred[buf][lane][wid] = wv;
        __syncthreads();
        float vtmp = 0.f;
        {
            const float4 r0 = *(const float4*)&wred[buf][lane < 15 ? lane : 0][0];
            const float4 r1 = *(const float4*)&wred[buf][lane < 15 ? lane : 0][4];
            const float s = r0.x + r0.y + r0.z + r0.w + r1.x + r1.y + r1.z + r1.w;
            vtmp = mybm * __builtin_amdgcn_rcpf(s + 1e-16f);
        }
        #pragma unroll
        for (int m = 0; m < 15; m++) vloc[m] = rdlane(vtmp, m);
        #pragma unroll
        for (int j = 0; j < 8; j++) {
            float s = 0.f;
            #pragma unroll
            for (int m = 0; m < 15; m++) s += K[j][m] * vloc[m];
            u[j] = a_n * __builtin_amdgcn_rcpf(s + 1e-16f);
        }
    }
    #pragma unroll
    for (int j = 0; j < 8; j++) {
        const int n = t + j * 512;
        float bv = -3e38f;
        int bi = 0;
        union { uint4 u4[4]; _Float16 h[32]; } ob;
        #pragma unroll
        for (int m = 0; m < 14; m++) {
            const float tv = fmaxf(4096.f * u[j] * K[j][m] * vloc[m], 0.f);
            const _Float16 hh = (_Float16)tv;
            ob.h[m] = hh;
            ob.h[16 + m] = (_Float16)(tv - (float)hh);
            if (tv > bv) { bv = tv; bi = m; }
        }
        ob.h[14] = (_Float16)0.f; ob.h[15] = (_Float16)0.f;
        ob.h[30] = (_Float16)0.f; ob.h[31] = (_Float16)0.f;
        uint4* dst = (uint4*)(as2ph + ((size_t)(b * 4096 + n)) * 32);
        dst[0] = ob.u4[0]; dst[1] = ob.u4[1];
        dst[2] = ob.u4[2]; dst[3] = ob.u4[3];
        int msk = 1 << bi;
        if (bi == 0) msk |= (1 << 12);
        else if (bi == 12) msk |= 1;
        else if (bi == 3) msk |= (1 << 11);
        else if (bi == 11) msk |= (1 << 3);
        code[b * 4096 + n] = msk | (valid[b * 4096 + n] << 14);
    }
}

// ---------------------------------------------------------------- lam table
__global__ __launch_bounds__(256) void k_lamtab(const int* __restrict__ code,
                                                int* __restrict__ lamtab) {
    const int b = blockIdx.x, t = threadIdx.x;
    __shared__ int sm0[4], sm1[4];
    int m0 = 0, m1 = 0;
    for (int m = t; m < 4096; m += 256) {
        const int c = code[b * 4096 + m];
        const int mask = c & 0x3fff;
        const int v = c >> 14;
        const int nmask = (~mask) & 0x3fff;
        if (v == 0) { m0 |= mask; m1 |= nmask; }
        else { m1 |= mask; }
    }
    #pragma unroll
    for (int off = 32; off; off >>= 1) {
        m0 |= __shfl_xor(m0, off, 64);
        m1 |= __shfl_xor(m1, off, 64);
    }
    if ((t & 63) == 0) { sm0[t >> 6] = m0; sm1[t >> 6] = m1; }
    __syncthreads();
    if (t == 0) {
        lamtab[b * 2 + 0] = sm0[0] | sm0[1] | sm0[2] | sm0[3];
        lamtab[b * 2 + 1] = sm1[0] | sm1[1] | sm1[2] | sm1[3];
    }
}

// ---------------------------------------------------------------- fused P + PV
__global__ __launch_bounds__(512, 2) void k_fused(const float* __restrict__ aq2p,
                                                  const _Float16* __restrict__ as2ph,
                                                  const int* __restrict__ code,
                                                  const int* __restrict__ sidq,
                                                  const int* __restrict__ lamtab,
                                                  const _Float16* __restrict__ vvT_h,
                                                  float* __restrict__ y) {
    const int bid = blockIdx.x;
    const int xcd = bid & 7, slot = bid >> 3;
    const int b = xcd >> 1;                       // 2 XCDs per batch
    const int n0 = ((xcd & 1) * 64 + slot) * 32;
    const int t = threadIdx.x;
    const int l = t & 63, wv = t >> 6;
    const int wn = wv & 1, wcS = wv >> 1;         // S-phase wave role
    const int quad = l >> 4, lr = l & 15;

    __shared__ __align__(16) _Float16 Pl[2][32 * 128];  // double-buffered P tile
    __shared__ float rsl[4][32];
    __shared__ int ssq[32], sml[32];
    __shared__ float rinv_s[32];

    if (t < 32) {
        const int sq = sidq[b * 4096 + n0 + t];
        const int lm0 = lamtab[b * 2], lm1 = lamtab[b * 2 + 1];
        ssq[t] = sq;
        sml[t] = ((lm0 >> sq) & 1) ? 0 : (((lm1 >> sq) & 1) ? 1 : 2);
    }
    __syncthreads();
    int sqp = 0;
    #pragma unroll
    for (int r = 0; r < 4; r++) {
        const int row_l = wn * 16 + quad * 4 + r;
        sqp |= (ssq[row_l] & 31) << (r * 8);
        sqp |= (sml[row_l] & 3) << (r * 8 + 5);
    }
    UH8 a1, a2;
    {
        const float* arow = aq2p + ((size_t)(b * 4096 + n0 + wn * 16 + lr)) * 14;
        const int kb = (quad & 1) * 8;
        #pragma unroll
        for (int j = 0; j < 8; j++) {
            const int kk2 = kb + j;
            const float f = (kk2 < 14) ? arow[kk2] : 0.f;
            const _Float16 hi = (_Float16)f;
            a1.h[j] = hi;
            a2.h[j] = (quad < 2) ? (_Float16)(f - (float)hi) : (_Float16)0.f;
        }
    }
    const _Float16* a2base = as2ph + (size_t)b * 4096 * 32 + quad * 8;
    const int* cbase = code + b * 4096;
    const _Float16* bvb0 = vvT_h + ((size_t)(b * 256 + wv * 32 + lr)) * 4096 + quad * 8;
    const _Float16* bvb1 = bvb0 + (size_t)16 * 4096;

    UH8 bS[2];
    int cdr[2];
    #pragma unroll
    for (int i = 0; i < 2; i++) {
        const int m = (wcS * 2 + i) * 16 + lr;
        bS[i].u4 = *(const uint4*)(a2base + (size_t)m * 32);
        cdr[i] = cbase[m];
    }
    UH8 bA[8], bB[8];
    #pragma unroll
    for (int ms = 0; ms < 4; ms++) {
        bA[ms * 2 + 0].u4 = *(const uint4*)(bvb0 + ms * 32);
        bA[ms * 2 + 1].u4 = *(const uint4*)(bvb1 + ms * 32);
    }
    f32x4 acc[2][2];
    #pragma unroll
    for (int fr = 0; fr < 2; fr++)
        #pragma unroll
        for (int ct = 0; ct < 2; ct++) acc[fr][ct] = (f32x4){0.f, 0.f, 0.f, 0.f};
    float rs4[4] = {0.f, 0.f, 0.f, 0.f};

#define FCHUNK(CUR, NXT, CH, LAST)                                             \
  {                                                                            \
    _Float16* PlW = Pl[(CH) & 1];                                              \
    _Pragma("unroll")                                                          \
    for (int i = 0; i < 2; i++) {                                              \
      f32x4 S = (f32x4){0.f, 0.f, 0.f, 0.f};                                   \
      S = __builtin_amdgcn_mfma_f32_16x16x32_f16(a1.h8, bS[i].h8, S, 0, 0, 0); \
      S = __builtin_amdgcn_mfma_f32_16x16x32_f16(a2.h8, bS[i].h8, S, 0, 0, 0); \
      const int cd = cdr[i];                                                   \
      const int mlocal = (wcS * 2 + i) * 16 + lr;                              \
      _Pragma("unroll")                                                        \
      for (int r = 0; r < 4; r++) {                                            \
        const int sq_r = (sqp >> (r * 8)) & 31;                                \
        const int ml_r = (sqp >> (r * 8 + 5)) & 3;                             \
        const int lvl = (cd >> 14) + 1 - ((cd >> sq_r) & 1);                   \
        const float p = (lvl == ml_r) ? __expf(S[r]) : 0.f;                    \
        rs4[r] += p;                                                           \
        const int nrow = wn * 16 + quad * 4 + r;                               \
        PlW[nrow * 128 + (mlocal ^ ((nrow & 7) << 3))] = (_Float16)p;          \
      }                                                                        \
    }                                                                          \
    if (!(LAST)) {                                                             \
      const int mcn = ((CH) + 1) * 128;                                        \
      _Pragma("unroll")                                                        \
      for (int i = 0; i < 2; i++) {                                            \
        const int m = mcn + (wcS * 2 + i) * 16 + lr;                           \
        bS[i].u4 = *(const uint4*)(a2base + (size_t)m * 32);                   \
        cdr[i] = cbase[m];                                                     \
      }                                                                        \
      _Pragma("unroll")                                                        \
      for (int ms = 0; ms < 4; ms++) {                                         \
        NXT[ms * 2 + 0].u4 = *(const uint4*)(bvb0 + mcn + ms * 32);            \
        NXT[ms * 2 + 1].u4 = *(const uint4*)(bvb1 + mcn + ms * 32);            \
      }                                                                        \
    }                                                                          \
    asm volatile("s_waitcnt lgkmcnt(0)" ::: "memory");                         \
    __builtin_amdgcn_s_barrier();                                              \
    asm volatile("" ::: "memory");                                             \
    const _Float16* PlR = Pl[(CH) & 1];                                        \
    __builtin_amdgcn_s_setprio(1);                                             \
    _Pragma("unroll")                                                          \
    for (int ms = 0; ms < 4; ms++) {                                           \
      UH8 aP0, aP1;                                                            \
      const int mb = ms * 32 + quad * 8;                                       \
      const int msw = mb ^ ((lr & 7) << 3);                                    \
      aP0.u4 = *(const uint4*)&PlR[lr * 128 + msw];                            \
      aP1.u4 = *(const uint4*)&PlR[(16 + lr) * 128 + msw];                     \
      acc[0][0] = __builtin_amdgcn_mfma_f32_16x16x32_f16(aP0.h8, CUR[ms * 2 + 0].h8, acc[0][0], 0, 0, 0); \
      acc[0][1] = __builtin_amdgcn_mfma_f32_16x16x32_f16(aP0.h8, CUR[ms * 2 + 1].h8, acc[0][1], 0, 0, 0); \
      acc[1][0] = __builtin_amdgcn_mfma_f32_16x16x32_f16(aP1.h8, CUR[ms * 2 + 0].h8, acc[1][0], 0, 0, 0); \
      acc[1][1] = __builtin_amdgcn_mfma_f32_16x16x32_f16(aP1.h8, CUR[ms * 2 + 1].h8, acc[1][1], 0, 0, 0); \
    }                                                                          \
    __builtin_amdgcn_s_setprio(0);                                             \
  }

    #pragma unroll 1
    for (int ch2 = 0; ch2 < 16; ch2++) {
        FCHUNK(bA, bB, ch2 * 2, false);
        FCHUNK(bB, bA, ch2 * 2 + 1, (ch2 == 15));
    }
#undef FCHUNK

    #pragma unroll
    for (int r = 0; r < 4; r++) {
        float v = rs4[r];
        v += __shfl_xor(v, 1, 64);
        v += __shfl_xor(v, 2, 64);
        v += __shfl_xor(v, 4, 64);
        v += __shfl_xor(v, 8, 64);
        rs4[r] = v;
    }
    __syncthreads();
    if (lr == 0) {
        #pragma unroll
        for (int r = 0; r < 4; r++) rsl[wcS][wn * 16 + quad * 4 + r] = rs4[r];
    }
    __syncthreads();
    if (t < 32) rinv_s[t] = 1.f / (rsl[0][t] + rsl[1][t] + rsl[2][t] + rsl[3][t]);
    __syncthreads();
    #pragma unroll
    for (int fr = 0; fr < 2; fr++)
        #pragma unroll
        for (int ct = 0; ct < 2; ct++)
            #pragma unroll
            for (int j = 0; j < 4; j++) {
                const int rowd = fr * 16 + quad * 4 + j;
                y[((size_t)b * 4096 + n0 + rowd) * 256 + wv * 32 + ct * 16 + lr] =
                    acc[fr][ct][j] * rinv_s[rowd];
            }
}

// ---------------------------------------------------------------- launch
extern "C" void kernel_launch(void* const* d_in, const int* in_sizes, int n_in,
                              void* d_out, int out_size, void* d_ws, size_t ws_size,
                              hipStream_t stream) {
    (void)in_sizes; (void)n_in; (void)out_size; (void)ws_size;
    const float* q    = (const float*)d_in[0];
    const float* k    = (const float*)d_in[1];
    const float* v    = (const float*)d_in[2];
    const float* sv   = (const float*)d_in[3];
    const int*  valid = (const int*)d_in[4];
    const int*  supp  = (const int*)d_in[5];
    const float* Wq   = (const float*)d_in[6];
    const float* Wk   = (const float*)d_in[7];
    const float* Wv   = (const float*)d_in[8];
    const float* Ws   = (const float*)d_in[9];
    const float* Wsq  = (const float*)d_in[10];
    const float* Wsk  = (const float*)d_in[11];
    const float* Wproj= (const float*)d_in[12];
    const float* Wqs  = (const float*)d_in[13];
    const float* Wks  = (const float*)d_in[14];
    const float* Wvs  = (const float*)d_in[15];
    const float* Wfc  = (const float*)d_in[16];
    const float* bfc  = (const float*)d_in[17];
    const float* lng  = (const float*)d_in[18];
    const float* lnb  = (const float*)d_in[19];

    float* ws = (float*)d_ws;
    // as2ph (fp16 4x4096x32 = 1 MB) overlays qs (dead after k_q2p)
    _Float16* as2ph = (_Float16*)ws;
    float* qs   = ws + 0;
    float* kk   = ws + 4194304;
    float* vv   = ws + 8388608;
    float* y0   = ws + 33554432;
    float* wqk2 = ws + 37748736;
    float* wcomb= ws + 37814272;
    float* seed = ws + 37879808;
    float* qhk  = ws + 37894144;
    float* logA = ws + 37908480;
    float* cpart= ws + 38137856;
    float* pkn  = ws + 38367232;
    float* pqn  = ws + 38381568;
    float* aq2p = ws + 38395904;
    float* attc = ws + 38625280;
    int* code   = (int*)(ws + 39084032);
    int* sidq   = (int*)(ws + 39100416);
    int* lamtab = (int*)(ws + 39116800);
    _Float16* vvT_h = (_Float16*)(ws + 39133216);

    gemm_aw3p<<<dim3(2, 256, 4), 256, 0, stream>>>(q, Wq, qs, k, Wk, kk, v, Wv, vv,
                                                   Wqs, Wks, wqk2, Wvs, Wfc, wcomb);
    k_seed<<<dim3(14, 4), 256, 0, stream>>>(sv, Ws, wqk2, seed, qhk);
    k_logits1<<<dim3(16, 4), 256, 0, stream>>>(kk, qhk, supp, logA);
    k_softmax1<<<dim3(14, 4), 256, 0, stream>>>(logA);
    k_ctxv<<<dim3(16, 4), 256, 0, stream>>>(logA, vv, cpart);
    k_proto<<<dim3(14, 4), 256, 0, stream>>>(cpart, wcomb, bfc, seed, lng, lnb, Wsk, Wsq, pkn, pqn);
    k_q2p<<<dim3(16, 4), 256, 0, stream>>>(qs, kk, pkn, pqn, aq2p, attc, sidq);
    k_sinkvv<<<516, 512, 0, stream>>>(attc, supp, valid, as2ph, code, vv, vvT_h);
    k_lamtab<<<4, 256, 0, stream>>>(code, lamtab);
    k_fused<<<dim3(512), 512, 0, stream>>>(aq2p, as2ph, code, sidq, lamtab, vvT_h, y0);
    gemm_aw<<<dim3(2, 256), 256, 0, stream>>>(y0, Wproj, (float*)d_out);
}